// Round 2
// baseline (1149.128 us; speedup 1.0000x reference)
//
#include <hip/hip_runtime.h>
#include <math.h>

// SimpleGCDEC: z = adj @ (x @ W) + b ; q = student-t soft assignment
// N=10000, NFEAT=3000, NHID=32, K=10, ALPHA=0.2
//
// Round 2: latency-bound fix. Double-buffered LDS GEMM with register-staged
// prefetch (loads for chunk c+1 issued before compute of chunk c), 3 blocks/CU
// (LDS 43 KB), grid 79x13. A-tile LDS stride 34 words -> 2-way bank aliasing
// on reads (free, m136). Per-f4 zero-fill guards handle all row/k tails.

#define NH     32      // NHID
#define KC     32      // k per chunk
#define TR     128     // rows per block
#define PAD_S  34      // LDS A row stride in words (KC+2): read starts 2 apart -> 2-way, free
#define NSPLIT 13      // split-K factor (grid = 79 x 13 = 1027 blocks ~ 3/CU)

__global__ __launch_bounds__(256, 3) void gemm_v2(
    const float* __restrict__ A,   // [M][K]
    const float* __restrict__ B,   // [K][32]
    float* __restrict__ outp,      // [NSPLIT][M][32] partials
    int M, int K, int nchunks)
{
    __shared__ float As[2][TR * PAD_S];   // 2*128*34*4 = 34816 B
    __shared__ float Bs[2][KC * NH];      // 2*32*32*4  =  8192 B  (total 43008)

    const int tid  = threadIdx.x;
    const int rg   = tid >> 3;         // 0..31 : rows rg + 32*m
    const int jg   = tid & 7;          // 0..7  : cols jg*4 .. +3
    const int row0 = blockIdx.x * TR;
    const int sy   = blockIdx.y;       // split index

    // staging assignment (fixed per thread):
    //   A: f4 slot a = p*256 + tid -> row_local = a>>3, c4 = a&7
    //   B: f4 slot tid             -> k_local = tid>>3, c4 = tid&7
    const int b_kl = tid >> 3;
    const int b_c4 = tid & 7;

    float4 acc[4];
#pragma unroll
    for (int m = 0; m < 4; ++m) acc[m] = make_float4(0.f, 0.f, 0.f, 0.f);

    float4 Ar[4];
    float4 Br;

    // ---------- prologue: load + write chunk sy into buffer 0 ----------
    {
        const int k0 = sy * KC;
#pragma unroll
        for (int p = 0; p < 4; ++p) {
            int a  = p * 256 + tid;
            int rl = a >> 3, c4 = a & 7;
            int gr = row0 + rl;
            int gk = k0 + (c4 << 2);
            Ar[p] = make_float4(0.f, 0.f, 0.f, 0.f);
            if (gr < M && gk < K)
                Ar[p] = *(const float4*)(A + (size_t)gr * K + gk);
        }
        {
            int gk = k0 + b_kl;
            Br = make_float4(0.f, 0.f, 0.f, 0.f);
            if (gk < K)
                Br = *(const float4*)(B + (size_t)gk * NH + (b_c4 << 2));
        }
#pragma unroll
        for (int p = 0; p < 4; ++p) {
            int a  = p * 256 + tid;
            int rl = a >> 3, c4 = a & 7;
            *(float4*)(&As[0][rl * PAD_S + (c4 << 2)]) = Ar[p];
        }
        *(float4*)(&Bs[0][b_kl * NH + (b_c4 << 2)]) = Br;
    }

    // ---------- main loop: chunks sy, sy+NSPLIT, ... ----------
    int buf = 0;
    for (int c = sy; c < nchunks; c += NSPLIT) {
        __syncthreads();   // buf is fully written for chunk c

        const int cn = c + NSPLIT;
        const bool has_next = (cn < nchunks);

        // prefetch chunk cn into registers (issued before compute)
        if (has_next) {
            const int k0 = cn * KC;
#pragma unroll
            for (int p = 0; p < 4; ++p) {
                int a  = p * 256 + tid;
                int rl = a >> 3, c4 = a & 7;
                int gr = row0 + rl;
                int gk = k0 + (c4 << 2);
                Ar[p] = make_float4(0.f, 0.f, 0.f, 0.f);
                if (gr < M && gk < K)
                    Ar[p] = *(const float4*)(A + (size_t)gr * K + gk);
            }
            int gk = cn * KC + b_kl;
            Br = make_float4(0.f, 0.f, 0.f, 0.f);
            if (gk < K)
                Br = *(const float4*)(B + (size_t)gk * NH + (b_c4 << 2));
        }

        // compute chunk c from LDS buf
        const float* Ab = &As[buf][0];
        const float* Bb = &Bs[buf][0];
#pragma unroll
        for (int kq = 0; kq < 8; ++kq) {
            float4 a[4];
#pragma unroll
            for (int m = 0; m < 4; ++m)
                a[m] = *(const float4*)(Ab + (rg + (m << 5)) * PAD_S + (kq << 2));
#pragma unroll
            for (int t = 0; t < 4; ++t) {
                float4 b = *(const float4*)(Bb + ((kq << 2) + t) * NH + (jg << 2));
#pragma unroll
                for (int m = 0; m < 4; ++m) {
                    float av = (t == 0) ? a[m].x : (t == 1) ? a[m].y
                             : (t == 2) ? a[m].z : a[m].w;
                    acc[m].x += av * b.x;
                    acc[m].y += av * b.y;
                    acc[m].z += av * b.z;
                    acc[m].w += av * b.w;
                }
            }
        }

        // write prefetched chunk into the other buffer
        if (has_next) {
            const int nb = buf ^ 1;
#pragma unroll
            for (int p = 0; p < 4; ++p) {
                int a  = p * 256 + tid;
                int rl = a >> 3, c4 = a & 7;
                *(float4*)(&As[nb][rl * PAD_S + (c4 << 2)]) = Ar[p];
            }
            *(float4*)(&Bs[nb][b_kl * NH + (b_c4 << 2)]) = Br;
        }
        buf ^= 1;
    }

    // ---------- store partials ----------
    float* op = outp + (size_t)sy * M * NH;
#pragma unroll
    for (int m = 0; m < 4; ++m) {
        int gr = row0 + rg + (m << 5);
        if (gr < M)
            *(float4*)(op + (size_t)gr * NH + (jg << 2)) = acc[m];
    }
}

__global__ __launch_bounds__(256) void reduce_add(
    const float* __restrict__ parts,  // [NSPLIT][total4] float4
    const float* __restrict__ bias,   // [32] or nullptr
    float* __restrict__ out,          // [total4] float4
    int total4)
{
    int i = blockIdx.x * blockDim.x + threadIdx.x;
    if (i >= total4) return;
    float4 s = make_float4(0.f, 0.f, 0.f, 0.f);
#pragma unroll
    for (int p = 0; p < NSPLIT; ++p) {
        float4 v = ((const float4*)parts)[(size_t)p * total4 + i];
        s.x += v.x; s.y += v.y; s.z += v.z; s.w += v.w;
    }
    if (bias) {
        float4 bv = ((const float4*)bias)[i & 7];   // f4 slot within the 32-wide row
        s.x += bv.x; s.y += bv.y; s.z += bv.z; s.w += bv.w;
    }
    ((float4*)out)[i] = s;
}

__global__ __launch_bounds__(256) void qkern(
    const float* __restrict__ z,   // [N][32]
    const float* __restrict__ mu,  // [10][32]
    float* __restrict__ q,         // [N][10]
    int N)
{
    const int tid  = threadIdx.x;
    const int lane = tid & 31;
    const int i    = blockIdx.x * 8 + (tid >> 5);
    if (i >= N) return;

    float zv = z[i * 32 + lane];
    float qm = 0.f, qsum = 0.f;
#pragma unroll
    for (int c = 0; c < 10; ++c) {
        float d = zv - mu[c * 32 + lane];
        float p = d * d;
#pragma unroll
        for (int m = 16; m >= 1; m >>= 1) p += __shfl_xor(p, m, 32);
        // q = (1 + d2/alpha + 1e-8)^-(alpha+1) / 2,  alpha = 0.2
        float t  = 1.0f + p * 5.0f + 1e-8f;
        float qc = powf(t, -1.2f) * 0.5f;
        qsum += qc;
        if (lane == c) qm = qc;
    }
    if (lane < 10) q[i * 10 + lane] = qm / qsum;
}

extern "C" void kernel_launch(void* const* d_in, const int* in_sizes, int n_in,
                              void* d_out, int out_size, void* d_ws, size_t ws_size,
                              hipStream_t stream)
{
    const float* x   = (const float*)d_in[0];   // [10000][3000]
    const float* adj = (const float*)d_in[1];   // [10000][10000]
    const float* W   = (const float*)d_in[2];   // [3000][32]
    const float* b   = (const float*)d_in[3];   // [32]
    const float* mu  = (const float*)d_in[4];   // [10][32]

    const int N = 10000, NFEAT = 3000;
    float* z_out = (float*)d_out;               // [10000][32]
    float* q_out = (float*)d_out + N * NH;      // [10000][10]

    float* ws_part    = (float*)d_ws;                           // NSPLIT * 320000 floats
    float* ws_support = (float*)d_ws + (size_t)NSPLIT * N * NH; // 320000 floats

    const int total4  = N * NH / 4;             // 80000
    const int rowBlks = (N + TR - 1) / TR;      // 79
    const int redBlks = (total4 + 255) / 256;   // 313

    // 1) support partials = x @ W
    {
        int nchunks = (NFEAT + KC - 1) / KC;    // 94
        gemm_v2<<<dim3(rowBlks, NSPLIT), 256, 0, stream>>>(
            x, W, ws_part, N, NFEAT, nchunks);
    }
    // 2) support = sum partials
    reduce_add<<<redBlks, 256, 0, stream>>>(ws_part, nullptr, ws_support, total4);
    // 3) z partials = adj @ support
    {
        int nchunks = (N + KC - 1) / KC;        // 313
        gemm_v2<<<dim3(rowBlks, NSPLIT), 256, 0, stream>>>(
            adj, ws_support, ws_part, N, N, nchunks);
    }
    // 4) z = sum partials + b  -> d_out
    reduce_add<<<redBlks, 256, 0, stream>>>(ws_part, b, z_out, total4);
    // 5) q from z -> d_out + 320000
    qkern<<<(N + 7) / 8, 256, 0, stream>>>(z_out, mu, q_out, N);
}